// Round 1
// baseline (3310.049 us; speedup 1.0000x reference)
//
#include <hip/hip_runtime.h>
#include <stdint.h>

// ---- problem constants ----
#define DIMC   384
#define NHEAD  12
#define HD     32
#define NTOK   49
#define BWIN   4096
#define NROWS  (BWIN * NTOK)     // 200704 token rows
#define K3     (3 * DIMC)        // 1152

typedef __bf16 bf16x8 __attribute__((ext_vector_type(8)));
typedef float  f32x4  __attribute__((ext_vector_type(4)));

static __device__ __forceinline__ ushort f2bf(float f) {
    uint32_t u = __float_as_uint(f);
    u += 0x7fffu + ((u >> 16) & 1u);      // RNE
    return (ushort)(u >> 16);
}
static __device__ __forceinline__ float bf2f(ushort s) {
    return __uint_as_float(((uint32_t)s) << 16);
}

// async global->LDS, 16B per lane (dest must be wave-contiguous: base + lane*16)
static __device__ __forceinline__ void async_ld16(const void* g, void* l) {
    __builtin_amdgcn_global_load_lds(
        (const __attribute__((address_space(1))) void*)g,
        (__attribute__((address_space(3))) void*)l,
        16, 0, 0);
}

// ---------------- fp32 -> bf16 convert (x4 vectorized, grid-stride) --------
__global__ void cvt_f32_bf16(const float* __restrict__ src,
                             ushort* __restrict__ dst, int n4) {
    int i = blockIdx.x * blockDim.x + threadIdx.x;
    int stride = gridDim.x * blockDim.x;
    for (; i < n4; i += stride) {
        float4 v = ((const float4*)src)[i];
        ushort4 o;
        o.x = f2bf(v.x); o.y = f2bf(v.y); o.z = f2bf(v.z); o.w = f2bf(v.w);
        ((ushort4*)dst)[i] = o;
    }
}

// ---------------- bf16 GEMM: C[m][n] = sum_k A[m][k] * Bw[n][k] + bias[n] --
// A: M x K bf16 row-major; Bw: Ncols x K bf16 row-major (i.e. B^T layout).
// 128x128 tile, BK=32, 256 threads = 4 waves in 2x2, each wave 64x64 via
// 4x4 x mfma_f32_16x16x32_bf16.  m97 structure (global_load_lds width 16).
template <bool OUT_F32>
__global__ void __launch_bounds__(256)
gemm_bt(const ushort* __restrict__ A, const ushort* __restrict__ Bw,
        const float* __restrict__ bias, void* __restrict__ Cout,
        int M, int Ncols, int K) {
    __shared__ ushort As[128 * 32];   // [row][k], row stride 32 elems (64B)
    __shared__ ushort Bs[128 * 32];

    const int t  = threadIdx.x;
    const int m0 = blockIdx.y * 128;
    const int n0 = blockIdx.x * 128;
    const int l  = t & 63;
    const int w  = t >> 6;
    const int wm = w & 1;            // wave row (0/1) -> 64 rows of M
    const int wn = w >> 1;           // wave col (0/1) -> 64 cols of N

    f32x4 acc[4][4] = {};

    // staging addresses: thread t loads 8 bf16 (16B); 256 threads cover 64 rows
    const int rowp = t >> 2;          // 0..63
    const int ch   = t & 3;           // 16B chunk within BK=32 row (4 chunks)
    const ushort* gA0 = A  + (size_t)(m0 + rowp) * K + ch * 8;
    const ushort* gA1 = gA0 + (size_t)64 * K;
    const ushort* gB0 = Bw + (size_t)(n0 + rowp) * K + ch * 8;
    const ushort* gB1 = gB0 + (size_t)64 * K;
    ushort* lA0 = &As[t * 8];
    ushort* lA1 = &As[2048 + t * 8];
    ushort* lB0 = &Bs[t * 8];
    ushort* lB1 = &Bs[2048 + t * 8];

    const int fr = l & 15;            // fragment row within 16
    const int kb = (l >> 4) * 8;      // fragment k-offset (quad*8)

    for (int kt = 0; kt < K; kt += 32) {
        async_ld16(gA0 + kt, lA0);
        async_ld16(gA1 + kt, lA1);
        async_ld16(gB0 + kt, lB0);
        async_ld16(gB1 + kt, lB1);
        __syncthreads();   // drains vmcnt, LDS tiles ready

        bf16x8 af[4], bfr[4];
#pragma unroll
        for (int mi = 0; mi < 4; ++mi)
            af[mi] = *(const bf16x8*)&As[(64 * wm + 16 * mi + fr) * 32 + kb];
#pragma unroll
        for (int ni = 0; ni < 4; ++ni)
            bfr[ni] = *(const bf16x8*)&Bs[(64 * wn + 16 * ni + fr) * 32 + kb];
#pragma unroll
        for (int mi = 0; mi < 4; ++mi)
#pragma unroll
            for (int ni = 0; ni < 4; ++ni)
                acc[mi][ni] = __builtin_amdgcn_mfma_f32_16x16x32_bf16(
                    af[mi], bfr[ni], acc[mi][ni], 0, 0, 0);
        __syncthreads();   // protect LDS before next stage
    }

    // epilogue: C/D layout col = lane&15, row = (lane>>4)*4 + reg
    const int colBase = n0 + 64 * wn + fr;
    const int rowBase = m0 + 64 * wm + ((l >> 4) << 2);
#pragma unroll
    for (int mi = 0; mi < 4; ++mi) {
#pragma unroll
        for (int ni = 0; ni < 4; ++ni) {
            const int col = colBase + 16 * ni;
            const float bv = bias[col];
#pragma unroll
            for (int r = 0; r < 4; ++r) {
                const int row = rowBase + 16 * mi + r;
                const float v = acc[mi][ni][r] + bv;
                if (OUT_F32)
                    ((float*)Cout)[(size_t)row * Ncols + col] = v;
                else
                    ((ushort*)Cout)[(size_t)row * Ncols + col] = f2bf(v);
            }
        }
    }
}

// ---------------- attention: one wave per (window b, head h) ---------------
// qkv: NROWS x 1152 bf16, col = s*384 + h*32 + d.  y: NROWS x 384 bf16 out.
__global__ void __launch_bounds__(64)
attn_kernel(const ushort* __restrict__ qkv, const float* __restrict__ mask,
            const float* __restrict__ bias_table,
            const int* __restrict__ rel_index, ushort* __restrict__ y) {
    const int h = blockIdx.x;
    const int b = blockIdx.y;
    __shared__ ushort Kt[NTOK * HD];
    __shared__ ushort Vt[NTOK * HD];
    __shared__ float  biasc[169];

    const int t = threadIdx.x;
    const size_t rowbase = (size_t)b * NTOK * K3;

    // stage K,V (bf16, 16B chunks): 49*32/8 = 196 chunks
    for (int c = t; c < 196; c += 64) {
        const int j  = c >> 2;
        const int dc = (c & 3) * 8;
        const ushort* kp = qkv + rowbase + (size_t)j * K3 + DIMC + h * HD + dc;
        *(uint4*)&Kt[j * HD + dc] = *(const uint4*)kp;
        *(uint4*)&Vt[j * HD + dc] = *(const uint4*)(kp + DIMC);
    }
    for (int i2 = t; i2 < 169; i2 += 64) biasc[i2] = bias_table[i2 * NHEAD + h];
    __syncthreads();

    const int i = t;
    if (i >= NTOK) return;   // no further barriers

    // q row -> registers, pre-scaled
    float q[HD];
    {
        const ushort* qp = qkv + rowbase + (size_t)i * K3 + h * HD;
        const float scale = 0.17677669529663687f;   // 32^-0.5
#pragma unroll
        for (int dc = 0; dc < 4; ++dc) {
            uint4 raw = *(const uint4*)(qp + dc * 8);
            const ushort* rs = (const ushort*)&raw;
#pragma unroll
            for (int e = 0; e < 8; ++e) q[dc * 8 + e] = bf2f(rs[e]) * scale;
        }
    }

    const float* mrow = mask + ((size_t)(b & 63) * NTOK + i) * NTOK;
    const int*   rrow = rel_index + i * NTOK;

    float s[NTOK];
    float mx = -3.0e38f;
#pragma unroll
    for (int j = 0; j < NTOK; ++j) {
        float sum = 0.f;
#pragma unroll
        for (int dc = 0; dc < 4; ++dc) {
            uint4 raw = *(const uint4*)&Kt[j * HD + dc * 8];
            const ushort* rs = (const ushort*)&raw;
#pragma unroll
            for (int e = 0; e < 8; ++e) sum += q[dc * 8 + e] * bf2f(rs[e]);
        }
        sum += biasc[rrow[j]] + mrow[j];
        s[j] = sum;
        mx = fmaxf(mx, sum);
    }
    float den = 0.f;
#pragma unroll
    for (int j = 0; j < NTOK; ++j) {
        const float e = __expf(s[j] - mx);
        s[j] = e;
        den += e;
    }
    const float inv = 1.0f / den;

    float o[HD];
#pragma unroll
    for (int d = 0; d < HD; ++d) o[d] = 0.f;
#pragma unroll
    for (int j = 0; j < NTOK; ++j) {
        const float p = s[j] * inv;
#pragma unroll
        for (int dc = 0; dc < 4; ++dc) {
            uint4 raw = *(const uint4*)&Vt[j * HD + dc * 8];
            const ushort* rs = (const ushort*)&raw;
#pragma unroll
            for (int e = 0; e < 8; ++e) o[dc * 8 + e] += p * bf2f(rs[e]);
        }
    }

    ushort* yp = y + ((size_t)(b * NTOK + i)) * DIMC + h * HD;
#pragma unroll
    for (int dc = 0; dc < 4; ++dc) {
        uint4 w4;
        uint32_t* wp = (uint32_t*)&w4;
#pragma unroll
        for (int e = 0; e < 4; ++e) {
            const uint32_t lo = f2bf(o[dc * 8 + 2 * e]);
            const uint32_t hi = f2bf(o[dc * 8 + 2 * e + 1]);
            wp[e] = lo | (hi << 16);
        }
        *(uint4*)(yp + dc * 8) = w4;
    }
}

// ---------------- launch ----------------
extern "C" void kernel_launch(void* const* d_in, const int* in_sizes, int n_in,
                              void* d_out, int out_size, void* d_ws, size_t ws_size,
                              hipStream_t stream) {
    const float* x          = (const float*)d_in[0];
    const float* mask       = (const float*)d_in[1];
    const float* qkv_w      = (const float*)d_in[2];
    const float* qkv_b      = (const float*)d_in[3];
    const float* proj_w     = (const float*)d_in[4];
    const float* proj_b     = (const float*)d_in[5];
    const float* bias_table = (const float*)d_in[6];
    const int*   rel_index  = (const int*)d_in[7];

    // workspace layout (ushort elements)
    ushort* ws   = (ushort*)d_ws;
    ushort* xb   = ws;                                   // 77,070,336  (x bf16; reused as y)
    ushort* wqkv = ws + (size_t)77070336;                // 442,368
    ushort* wprj = ws + (size_t)77070336 + 442368;       // 147,456
    ushort* qkvb = ws + (size_t)77070336 + 442368 + 147456; // 231,211,008

    // 1) converts
    cvt_f32_bf16<<<4096, 256, 0, stream>>>(x, xb, (NROWS * DIMC) / 4);
    cvt_f32_bf16<<<432, 256, 0, stream>>>(qkv_w, wqkv, (K3 * DIMC) / 4);
    cvt_f32_bf16<<<144, 256, 0, stream>>>(proj_w, wprj, (DIMC * DIMC) / 4);

    // 2) QKV GEMM: (200704x384) @ (1152x384)^T -> qkv bf16
    gemm_bt<false><<<dim3(K3 / 128, NROWS / 128), 256, 0, stream>>>(
        xb, wqkv, qkv_b, qkvb, NROWS, K3, DIMC);

    // 3) attention -> y (bf16, aliases xb)
    attn_kernel<<<dim3(NHEAD, BWIN), 64, 0, stream>>>(
        qkvb, mask, bias_table, rel_index, xb);

    // 4) proj GEMM: (200704x384) @ (384x384)^T -> d_out fp32
    gemm_bt<true><<<dim3(DIMC / 128, NROWS / 128), 256, 0, stream>>>(
        xb, wprj, proj_b, d_out, NROWS, DIMC, DIMC);
}